// Round 9
// baseline (472.847 us; speedup 1.0000x reference)
//
#include <hip/hip_runtime.h>
#include <cstdint>

#define N 8192
#define FIN 256
#define FOUT 128
#define ALPHA 0.2f

typedef unsigned short u16;
typedef __attribute__((ext_vector_type(8))) short short8;
typedef __attribute__((ext_vector_type(4))) float floatx4;

__device__ __forceinline__ u16 bf16_rne(float f) {
  uint32_t u = __float_as_uint(f);
  u += 0x7fff + ((u >> 16) & 1);
  return (u16)(u >> 16);
}

__device__ __forceinline__ void gl_lds16(const void* g, void* l) {
  __builtin_amdgcn_global_load_lds(
      (const __attribute__((address_space(1))) void*)g,
      (__attribute__((address_space(3))) void*)l, 16, 0, 0);
}

// ---------------------------------------------------------------------------
// Kernel 1: h = x@W (fp32); hT3 bf16 tiled [jb][nt][m*4+q][8]; src/dst.
// (unchanged — isolated; it is the next optimization target)
// ---------------------------------------------------------------------------
__global__ __launch_bounds__(256) void k_proj(const float* __restrict__ x,
                                              const float* __restrict__ W,
                                              const float* __restrict__ a,
                                              u16* __restrict__ hT3,
                                              float* __restrict__ srcv,
                                              float* __restrict__ dstv) {
  __shared__ float xs[8 * FIN];
  __shared__ float partS[4][4], partD[4][4];
  const int t = threadIdx.x;
  const int R0 = blockIdx.x * 8;

  const float4* xv = (const float4*)(x + (size_t)R0 * FIN);
  float4* xsv = (float4*)xs;
  xsv[t] = xv[t];
  xsv[t + 256] = xv[t + 256];
  __syncthreads();

  const int c  = t & 127;
  const int rg = (t >> 7) * 4;

  float acc[4] = {0.f, 0.f, 0.f, 0.f};
  float wa[4], wb[4];
  #pragma unroll
  for (int j = 0; j < 4; ++j) wa[j] = W[j * FOUT + c];
  #pragma unroll
  for (int j = 0; j < 4; ++j) wb[j] = W[(4 + j) * FOUT + c];

  for (int k4 = 0; k4 < FIN / 4; ++k4) {
    float wc[4];
    #pragma unroll
    for (int j = 0; j < 4; ++j) { wc[j] = wa[j]; wa[j] = wb[j]; }
    const int kn = (k4 + 2 < FIN / 4) ? k4 + 2 : k4;
    #pragma unroll
    for (int j = 0; j < 4; ++j) wb[j] = W[(kn * 4 + j) * FOUT + c];
    #pragma unroll
    for (int i = 0; i < 4; ++i) {
      const float4 xq = *(const float4*)&xs[(rg + i) * FIN + k4 * 4];
      acc[i] += xq.x * wc[0] + xq.y * wc[1] + xq.z * wc[2] + xq.w * wc[3];
    }
  }

  {
    const int j = R0 + rg;
    const int jb = j >> 5, q = (j >> 3) & 3, jj = j & 7;
    const int m = c & 15, nt = c >> 4;
    union { u16 u[4]; uint2 v; } pk;
    #pragma unroll
    for (int i = 0; i < 4; ++i) pk.u[i] = bf16_rne(acc[i]);
    *(uint2*)(hT3 + (size_t)(((jb * 8 + nt) * 64) + (m * 4 + q)) * 8 + jj) = pk.v;
  }

  const float a1 = a[c], a2 = a[FOUT + c];
  float s4[4], d4[4];
  #pragma unroll
  for (int i = 0; i < 4; ++i) { s4[i] = acc[i] * a1; d4[i] = acc[i] * a2; }
  #pragma unroll
  for (int off = 32; off > 0; off >>= 1) {
    #pragma unroll
    for (int i = 0; i < 4; ++i) {
      s4[i] += __shfl_down(s4[i], off);
      d4[i] += __shfl_down(d4[i], off);
    }
  }
  const int wv = t >> 6, lane = t & 63;
  if (lane == 0) {
    #pragma unroll
    for (int i = 0; i < 4; ++i) { partS[wv][i] = s4[i]; partD[wv][i] = d4[i]; }
  }
  __syncthreads();
  if (t < 16) {
    const int i = t & 3, rg2 = (t >> 2) & 1, which = t >> 3;
    if (which == 0) srcv[R0 + rg2 * 4 + i] = partS[rg2*2][i] + partS[rg2*2+1][i];
    else            dstv[R0 + rg2 * 4 + i] = partD[rg2*2][i] + partD[rg2*2+1][i];
  }
}

// ---------------------------------------------------------------------------
// Kernel 2a (k_pgen): pure streaming P-generation. No barriers, no LDS, no
// cross-iteration deps — the compiler can pipeline it like a memcpy.
// Block = 16 rows x 4096-j half; pass = 64-j window across all 16 rows
// (1024 elems, 4/thread). Thread t -> row m=t>>4 (fixed for whole block, so
// row-sum accumulates privately; shfl-reduce at the end, no atomics).
// P written bf16 in the MFMA-tiled layout [rb16][kb32][m][q][jj]: each pass
// the block stores exactly 2 contiguous 1-KB tiles. adj reads row-major
// coalesced (16B/lane). Grid: rb(0..511) x jh(0..1) = 1024 blocks.
// ---------------------------------------------------------------------------
__global__ __launch_bounds__(256) void k_pgen(const int* __restrict__ adj,
                                              const float* __restrict__ srcv,
                                              const float* __restrict__ dstv,
                                              u16* __restrict__ Pt,
                                              float* __restrict__ lp) {
  const int t  = threadIdx.x;
  const int rb = blockIdx.x >> 1;        // 16-row block 0..511
  const int jh = blockIdx.x & 1;         // j half
  const int R0 = rb * 16;
  const int j0 = jh * 4096;
  const int m  = t >> 4;                 // this thread's row (fixed)
  const int sx = t & 15;

  const float srcr = srcv[R0 + m];
  const int*   ap = adj + (size_t)(R0 + m) * N + j0 + sx * 4;
  const float* dp = dstv + j0 + sx * 4;
  u16* pp = Pt + ((size_t)(rb * 256 + jh * 128 + (sx >> 3)) * 512)
               + m * 32 + ((sx & 7) * 4);

  float lsum = 0.f;
  #pragma unroll 4
  for (int kp = 0; kp < 64; ++kp) {
    const int4   A = *(const int4*)(ap + kp * 64);
    const float4 D = *(const float4*)(dp + kp * 64);
    const int   ai[4] = {A.x, A.y, A.z, A.w};
    const float df[4] = {D.x, D.y, D.z, D.w};
    union { u16 u[4]; uint2 v; } pk;
    #pragma unroll
    for (int e = 0; e < 4; ++e) {
      float v = srcr + df[e];
      v = fmaxf(v, ALPHA * v);
      const float p = ai[e] > 0 ? __expf(v) : 0.f;
      lsum += p;
      pk.u[e] = bf16_rne(p);
    }
    *(uint2*)(pp + (size_t)kp * 1024) = pk.v;   // 2 tiles (1024 u16) per pass
  }

  // row-sum: 16 lanes sharing row m are lane groups [g*16, g*16+16)
  lsum += __shfl_xor(lsum, 1);
  lsum += __shfl_xor(lsum, 2);
  lsum += __shfl_xor(lsum, 4);
  lsum += __shfl_xor(lsum, 8);
  if (sx == 0) lp[(size_t)jh * N + R0 + m] = lsum;
}

// ---------------------------------------------------------------------------
// Kernel 2b (k_av): clean DMA-staged GEMM  P2[ksp] = Pt @ hT3  (K-half).
// Block = 32 rows x 64 cols x 4096 K; K-tile = 64 (2 kb). Both operands
// arrive via global_load_lds (contiguous 1-KB chunks; NOTHING in the MFMA
// chain touches vmcnt). One barrier per tile, double-buffered LDS (24 KB).
// Grid: rb32(0..255) x ch(0..1) x ksp(0..1) = 1024 blocks, 4/CU.
// ---------------------------------------------------------------------------
__global__ __launch_bounds__(256, 4) void k_av(const u16* __restrict__ Pt,
                                               const u16* __restrict__ hT3,
                                               float* __restrict__ P2) {
  __shared__ u16 aS[2][4 * 512];     // 2 x 4 KB  (2 rb x 2 kb)
  __shared__ u16 bS[2][8 * 512];     // 2 x 8 KB  (2 jb x 4 nt)
  const int t = threadIdx.x, wv = t >> 6, lane = t & 63;
  const int q = lane >> 4, m = lane & 15, Lq = m * 4 + q;
  const int rb32 = blockIdx.x >> 2;
  const int ch   = (blockIdx.x >> 1) & 1;
  const int ksp  = blockIdx.x & 1;
  const int R0 = rb32 * 32;
  const int kb0 = ksp * 128;          // 32-k blocks in this half: kb0..kb0+127
  const int rh = wv & 1, ntp = wv >> 1;

  floatx4 acc[2];
  acc[0] = (floatx4){0.f, 0.f, 0.f, 0.f};
  acc[1] = (floatx4){0.f, 0.f, 0.f, 0.f};

  // stage K-tile I (kb = kb0+2I, +1): 12 chunks of 1 KB; wave wv does 3
  #define STAGE(I, BUF)                                                        \
  {                                                                            \
    _Pragma("unroll")                                                          \
    for (int cc = 0; cc < 3; ++cc) {                                           \
      const int d = wv * 3 + cc;                                               \
      if (d < 4) {                                                             \
        const int rr = d >> 1, kk = d & 1;                                     \
        const u16* s = Pt + ((size_t)((rb32 * 2 + rr) * 256 + kb0 + (I) * 2 + kk)) * 512 \
                       + (size_t)lane * 8;                                     \
        gl_lds16(s, &aS[BUF][d * 512]);                                        \
      } else {                                                                 \
        const int e = d - 4, jbx = e >> 2, nn = e & 3;                         \
        const u16* s = hT3 + ((size_t)(kb0 + (I) * 2 + jbx) * 8 + ch * 4 + nn) * 512 \
                       + (size_t)lane * 8;                                     \
        gl_lds16(s, &bS[BUF][e * 512]);                                        \
      }                                                                        \
    }                                                                          \
  }

  #define MFMA_TILE(BUF)                                                       \
  {                                                                            \
    _Pragma("unroll")                                                          \
    for (int kk = 0; kk < 2; ++kk) {                                           \
      const short8 af = *(const short8*)&aS[BUF][(rh * 2 + kk) * 512 + Lq * 8];\
      _Pragma("unroll")                                                        \
      for (int nn = 0; nn < 2; ++nn) {                                         \
        const short8 bf =                                                      \
            *(const short8*)&bS[BUF][(kk * 4 + ntp * 2 + nn) * 512 + Lq * 8];  \
        acc[nn] = __builtin_amdgcn_mfma_f32_16x16x32_bf16(af, bf, acc[nn], 0, 0, 0); \
      }                                                                        \
    }                                                                          \
  }

  STAGE(0, 0)
  for (int i = 0; i < 64; i += 2) {
    __syncthreads();                       // drains DMA(i) — 1 tile of cover
    { const int nx = (i + 1 < 64) ? i + 1 : i; STAGE(nx, 1) }
    MFMA_TILE(0)
    __syncthreads();                       // drains DMA(i+1)
    { const int nx = (i + 2 < 64) ? i + 2 : i + 1; STAGE(nx, 0) }
    MFMA_TILE(1)
  }
  #undef STAGE
  #undef MFMA_TILE
  __syncthreads();                         // drain dangling last DMA

  // store K-half partial: rows R0+rh*16+(q*4+ri), col ch*64+(ntp*2+nn)*16+m
  float* Pp = P2 + ((size_t)ksp * N + R0 + rh * 16) * FOUT + ch * 64 + ntp * 32 + m;
  #pragma unroll
  for (int nn = 0; nn < 2; ++nn)
    #pragma unroll
    for (int ri = 0; ri < 4; ++ri)
      Pp[(size_t)(q * 4 + ri) * FOUT + nn * 16] = acc[nn][ri];
}

// ---------------------------------------------------------------------------
// Kernel 3: combine 2 K-partials, normalize by row-sum (l = lp[0]+lp[1]).
// ---------------------------------------------------------------------------
__global__ __launch_bounds__(256) void k_norm(const float* __restrict__ P2,
                                              const float* __restrict__ lp,
                                              float* __restrict__ out) {
  const int idx = blockIdx.x * 256 + threadIdx.x;
  const int rr = idx >> 5;
  const int c4 = (idx & 31) * 4;
  const float inv = 1.0f / (lp[rr] + lp[N + rr]);
  const float4 p0 = *(const float4*)(P2 + (size_t)rr * FOUT + c4);
  const float4 p1 = *(const float4*)(P2 + ((size_t)N + rr) * FOUT + c4);
  float4 s;
  s.x = (p0.x + p1.x) * inv;
  s.y = (p0.y + p1.y) * inv;
  s.z = (p0.z + p1.z) * inv;
  s.w = (p0.w + p1.w) * inv;
  *(float4*)(out + (size_t)rr * FOUT + c4) = s;
}

extern "C" void kernel_launch(void* const* d_in, const int* in_sizes, int n_in,
                              void* d_out, int out_size, void* d_ws, size_t ws_size,
                              hipStream_t stream) {
  const float* x   = (const float*)d_in[0];
  const int*   adj = (const int*)d_in[1];
  const float* W   = (const float*)d_in[2];
  const float* a   = (const float*)d_in[3];
  float* out = (float*)d_out;

  char* ws = (char*)d_ws;
  u16*   hT3  = (u16*)ws;     ws += (size_t)FOUT * N * sizeof(u16);            // 2 MB
  float* srcv = (float*)ws;   ws += (size_t)N * sizeof(float);
  float* dstv = (float*)ws;   ws += (size_t)N * sizeof(float);
  u16*   Pt   = (u16*)ws;     ws += (size_t)N * N * sizeof(u16);               // 128 MB
  float* lp   = (float*)ws;   ws += (size_t)2 * N * sizeof(float);
  float* P2   = (float*)ws;   ws += (size_t)2 * N * FOUT * sizeof(float);      // 8 MB

  k_proj<<<N / 8, 256, 0, stream>>>(x, W, a, hT3, srcv, dstv);
  k_pgen<<<1024, 256, 0, stream>>>(adj, srcv, dstv, Pt, lp);
  k_av  <<<1024, 256, 0, stream>>>(Pt, hT3, P2);
  k_norm<<<(N * FOUT / 4) / 256, 256, 0, stream>>>(P2, lp, out);
}

// Round 10
// 462.890 us; speedup vs baseline: 1.0215x; 1.0215x over previous
//
#include <hip/hip_runtime.h>
#include <cstdint>

#define N 8192
#define FIN 256
#define FOUT 128
#define ALPHA 0.2f

typedef unsigned short u16;
typedef __attribute__((ext_vector_type(8))) short short8;
typedef __attribute__((ext_vector_type(4))) float floatx4;

__device__ __forceinline__ u16 bf16_rne(float f) {
  uint32_t u = __float_as_uint(f);
  u += 0x7fff + ((u >> 16) & 1);
  return (u16)(u >> 16);
}

__device__ __forceinline__ void gl_lds16(const void* g, void* l) {
  __builtin_amdgcn_global_load_lds(
      (const __attribute__((address_space(1))) void*)g,
      (__attribute__((address_space(3))) void*)l, 16, 0, 0);
}

// ---------------------------------------------------------------------------
// Kernel 1: h = x@W (fp32); hT3 bf16 tiled [jb][nt][m*4+q][8]; src/dst.
// (unchanged)
// ---------------------------------------------------------------------------
__global__ __launch_bounds__(256) void k_proj(const float* __restrict__ x,
                                              const float* __restrict__ W,
                                              const float* __restrict__ a,
                                              u16* __restrict__ hT3,
                                              float* __restrict__ srcv,
                                              float* __restrict__ dstv) {
  __shared__ float xs[8 * FIN];
  __shared__ float partS[4][4], partD[4][4];
  const int t = threadIdx.x;
  const int R0 = blockIdx.x * 8;

  const float4* xv = (const float4*)(x + (size_t)R0 * FIN);
  float4* xsv = (float4*)xs;
  xsv[t] = xv[t];
  xsv[t + 256] = xv[t + 256];
  __syncthreads();

  const int c  = t & 127;
  const int rg = (t >> 7) * 4;

  float acc[4] = {0.f, 0.f, 0.f, 0.f};
  float wa[4], wb[4];
  #pragma unroll
  for (int j = 0; j < 4; ++j) wa[j] = W[j * FOUT + c];
  #pragma unroll
  for (int j = 0; j < 4; ++j) wb[j] = W[(4 + j) * FOUT + c];

  for (int k4 = 0; k4 < FIN / 4; ++k4) {
    float wc[4];
    #pragma unroll
    for (int j = 0; j < 4; ++j) { wc[j] = wa[j]; wa[j] = wb[j]; }
    const int kn = (k4 + 2 < FIN / 4) ? k4 + 2 : k4;
    #pragma unroll
    for (int j = 0; j < 4; ++j) wb[j] = W[(kn * 4 + j) * FOUT + c];
    #pragma unroll
    for (int i = 0; i < 4; ++i) {
      const float4 xq = *(const float4*)&xs[(rg + i) * FIN + k4 * 4];
      acc[i] += xq.x * wc[0] + xq.y * wc[1] + xq.z * wc[2] + xq.w * wc[3];
    }
  }

  {
    const int j = R0 + rg;
    const int jb = j >> 5, q = (j >> 3) & 3, jj = j & 7;
    const int m = c & 15, nt = c >> 4;
    union { u16 u[4]; uint2 v; } pk;
    #pragma unroll
    for (int i = 0; i < 4; ++i) pk.u[i] = bf16_rne(acc[i]);
    *(uint2*)(hT3 + (size_t)(((jb * 8 + nt) * 64) + (m * 4 + q)) * 8 + jj) = pk.v;
  }

  const float a1 = a[c], a2 = a[FOUT + c];
  float s4[4], d4[4];
  #pragma unroll
  for (int i = 0; i < 4; ++i) { s4[i] = acc[i] * a1; d4[i] = acc[i] * a2; }
  #pragma unroll
  for (int off = 32; off > 0; off >>= 1) {
    #pragma unroll
    for (int i = 0; i < 4; ++i) {
      s4[i] += __shfl_down(s4[i], off);
      d4[i] += __shfl_down(d4[i], off);
    }
  }
  const int wv = t >> 6, lane = t & 63;
  if (lane == 0) {
    #pragma unroll
    for (int i = 0; i < 4; ++i) { partS[wv][i] = s4[i]; partD[wv][i] = d4[i]; }
  }
  __syncthreads();
  if (t < 16) {
    const int i = t & 3, rg2 = (t >> 2) & 1, which = t >> 3;
    if (which == 0) srcv[R0 + rg2 * 4 + i] = partS[rg2*2][i] + partS[rg2*2+1][i];
    else            dstv[R0 + rg2 * 4 + i] = partD[rg2*2][i] + partD[rg2*2+1][i];
  }
}

// ---------------------------------------------------------------------------
// Kernel 2a (k_pgen): streaming P-generation. Occupancy/MLP fix vs round 9:
// grid 2048 (8 blocks/CU, 32 waves/CU), launch_bounds(256,8) caps VGPR at 64,
// unroll-8 over fully independent passes -> deep load window. Block = 16 rows
// x 2048-j slice; thread t -> row m=t>>4 (private row-sum, shfl-reduced).
// Pt written bf16 in MFMA-tiled layout [rb16][kb32][m][q][jj] (2 contiguous
// 1-KB tiles per pass per block).
// ---------------------------------------------------------------------------
__global__ __launch_bounds__(256, 8) void k_pgen(const int* __restrict__ adj,
                                                 const float* __restrict__ srcv,
                                                 const float* __restrict__ dstv,
                                                 u16* __restrict__ Pt,
                                                 float* __restrict__ lp) {
  const int t  = threadIdx.x;
  const int rb = blockIdx.x & 511;       // 16-row block
  const int js = blockIdx.x >> 9;        // j slice 0..3 (2048 j each)
  const int R0 = rb * 16;
  const int j0 = js * 2048;
  const int m  = t >> 4;                 // this thread's row (fixed)
  const int sx = t & 15;

  const float srcr = srcv[R0 + m];
  const int*   ap = adj + (size_t)(R0 + m) * N + j0 + sx * 4;
  const float* dp = dstv + j0 + sx * 4;
  u16* pp = Pt + ((size_t)(rb * 256 + js * 64 + (sx >> 3)) * 512)
               + m * 32 + ((sx & 7) * 4);

  float lsum = 0.f;
  #pragma unroll 8
  for (int kp = 0; kp < 32; ++kp) {
    const int4   A = *(const int4*)(ap + kp * 64);
    const float4 D = *(const float4*)(dp + kp * 64);
    const int   ai[4] = {A.x, A.y, A.z, A.w};
    const float df[4] = {D.x, D.y, D.z, D.w};
    union { u16 u[4]; uint2 v; } pk;
    #pragma unroll
    for (int e = 0; e < 4; ++e) {
      float v = srcr + df[e];
      v = fmaxf(v, ALPHA * v);
      const float p = ai[e] > 0 ? __expf(v) : 0.f;
      lsum += p;
      pk.u[e] = bf16_rne(p);
    }
    *(uint2*)(pp + (size_t)kp * 1024) = pk.v;
  }

  lsum += __shfl_xor(lsum, 1);
  lsum += __shfl_xor(lsum, 2);
  lsum += __shfl_xor(lsum, 4);
  lsum += __shfl_xor(lsum, 8);
  if (sx == 0) lp[(size_t)js * N + R0 + m] = lsum;
}

// ---------------------------------------------------------------------------
// Kernel 2b (k_av): DMA-staged GEMM  P4[ksp] = Pt @ hT3  (K-quarter).
// vs round 9: 64 rows/block (halves+quarters hT3 L2 re-reads: 512->128 MB)
// and K-split 4. Per 64-K tile: A 8 KB + B 8 KB staged via global_load_lds
// (16 chunks, 4/wave), double-buffered (32 KB LDS, 4 blocks/CU), one barrier
// per tile, 8 MFMAs/wave/tile. Grid: rb64(0..127) x ch(0..1) x ksp(0..3).
// ---------------------------------------------------------------------------
__global__ __launch_bounds__(256, 4) void k_av(const u16* __restrict__ Pt,
                                               const u16* __restrict__ hT3,
                                               float* __restrict__ P4) {
  __shared__ u16 aS[2][8 * 512];     // 2 x 8 KB
  __shared__ u16 bS[2][8 * 512];     // 2 x 8 KB
  const int t = threadIdx.x, wv = t >> 6, lane = t & 63;
  const int q = lane >> 4, m = lane & 15, Lq = m * 4 + q;
  const int rb64 = blockIdx.x & 127;
  const int ch   = (blockIdx.x >> 7) & 1;
  const int ksp  = blockIdx.x >> 8;
  const int kb0  = ksp * 64;          // 64 kb32 per K-quarter (2048 k)

  floatx4 acc[4];
  #pragma unroll
  for (int nn = 0; nn < 4; ++nn) acc[nn] = (floatx4){0.f, 0.f, 0.f, 0.f};

  // stage K-tile I (kb = kb0 + 2I + kk): 16 chunks of 1 KB; wave wv does 4
  #define STAGE(I, BUF)                                                        \
  {                                                                            \
    _Pragma("unroll")                                                          \
    for (int cc = 0; cc < 4; ++cc) {                                           \
      const int d = wv * 4 + cc;                                               \
      if (d < 8) {        /* A: rr = d>>1, kk = d&1 */                         \
        const int rr = d >> 1, kk = d & 1;                                     \
        const u16* s = Pt + ((size_t)((rb64 * 4 + rr) * 256 + kb0 + (I) * 2 + kk)) * 512 \
                       + (size_t)lane * 8;                                     \
        gl_lds16(s, &aS[BUF][d * 512]);                                        \
      } else {            /* B: e = d-8, kk = e>>2, nn = e&3 */                \
        const int e = d - 8, kk = e >> 2, nn = e & 3;                          \
        const u16* s = hT3 + ((size_t)(kb0 + (I) * 2 + kk) * 8 + ch * 4 + nn) * 512 \
                       + (size_t)lane * 8;                                     \
        gl_lds16(s, &bS[BUF][e * 512]);                                        \
      }                                                                        \
    }                                                                          \
  }

  #define MFMA_TILE(BUF)                                                       \
  {                                                                            \
    _Pragma("unroll")                                                          \
    for (int kk = 0; kk < 2; ++kk) {                                           \
      const short8 af = *(const short8*)&aS[BUF][(wv * 2 + kk) * 512 + Lq * 8];\
      _Pragma("unroll")                                                        \
      for (int nn = 0; nn < 4; ++nn) {                                         \
        const short8 bf =                                                      \
            *(const short8*)&bS[BUF][(kk * 4 + nn) * 512 + Lq * 8];            \
        acc[nn] = __builtin_amdgcn_mfma_f32_16x16x32_bf16(af, bf, acc[nn], 0, 0, 0); \
      }                                                                        \
    }                                                                          \
  }

  STAGE(0, 0)
  for (int i = 0; i < 32; i += 2) {
    __syncthreads();                       // drains DMA(i)
    { const int nx = (i + 1 < 32) ? i + 1 : i; STAGE(nx, 1) }
    MFMA_TILE(0)
    __syncthreads();                       // drains DMA(i+1)
    { const int nx = (i + 2 < 32) ? i + 2 : i + 1; STAGE(nx, 0) }
    MFMA_TILE(1)
  }
  #undef STAGE
  #undef MFMA_TILE

  // store: rows rb64*64 + wv*16 + (q*4+ri), cols ch*64 + nn*16 + m
  float* Pp = P4 + ((size_t)ksp * N + rb64 * 64 + wv * 16) * FOUT + ch * 64 + m;
  #pragma unroll
  for (int nn = 0; nn < 4; ++nn)
    #pragma unroll
    for (int ri = 0; ri < 4; ++ri)
      Pp[(size_t)(q * 4 + ri) * FOUT + nn * 16] = acc[nn][ri];
}

// ---------------------------------------------------------------------------
// Kernel 3: combine 4 K-partials + 4 l-partials, normalize.
// ---------------------------------------------------------------------------
__global__ __launch_bounds__(256) void k_norm(const float* __restrict__ P4,
                                              const float* __restrict__ lp,
                                              float* __restrict__ out) {
  const int idx = blockIdx.x * 256 + threadIdx.x;
  const int rr = idx >> 5;
  const int c4 = (idx & 31) * 4;
  float l = 0.f;
  #pragma unroll
  for (int s = 0; s < 4; ++s) l += lp[(size_t)s * N + rr];
  const float inv = 1.0f / l;
  float4 s = {0.f, 0.f, 0.f, 0.f};
  #pragma unroll
  for (int p = 0; p < 4; ++p) {
    const float4 v = *(const float4*)(P4 + ((size_t)p * N + rr) * FOUT + c4);
    s.x += v.x; s.y += v.y; s.z += v.z; s.w += v.w;
  }
  s.x *= inv; s.y *= inv; s.z *= inv; s.w *= inv;
  *(float4*)(out + (size_t)rr * FOUT + c4) = s;
}

extern "C" void kernel_launch(void* const* d_in, const int* in_sizes, int n_in,
                              void* d_out, int out_size, void* d_ws, size_t ws_size,
                              hipStream_t stream) {
  const float* x   = (const float*)d_in[0];
  const int*   adj = (const int*)d_in[1];
  const float* W   = (const float*)d_in[2];
  const float* a   = (const float*)d_in[3];
  float* out = (float*)d_out;

  char* ws = (char*)d_ws;
  u16*   hT3  = (u16*)ws;     ws += (size_t)FOUT * N * sizeof(u16);            // 2 MB
  float* srcv = (float*)ws;   ws += (size_t)N * sizeof(float);
  float* dstv = (float*)ws;   ws += (size_t)N * sizeof(float);
  u16*   Pt   = (u16*)ws;     ws += (size_t)N * N * sizeof(u16);               // 128 MB
  float* lp   = (float*)ws;   ws += (size_t)4 * N * sizeof(float);
  float* P4   = (float*)ws;   ws += (size_t)4 * N * FOUT * sizeof(float);      // 16 MB

  k_proj<<<N / 8, 256, 0, stream>>>(x, W, a, hT3, srcv, dstv);
  k_pgen<<<2048, 256, 0, stream>>>(adj, srcv, dstv, Pt, lp);
  k_av  <<<1024, 256, 0, stream>>>(Pt, hT3, P4);
  k_norm<<<(N * FOUT / 4) / 256, 256, 0, stream>>>(P4, lp, out);
}

// Round 11
// 462.394 us; speedup vs baseline: 1.0226x; 1.0011x over previous
//
#include <hip/hip_runtime.h>
#include <cstdint>

#define N 8192
#define FIN 256
#define FOUT 128
#define ALPHA 0.2f
#define JP 4                  // j-split for k_gat
#define JSL (N / JP)          // 2048 j per block
#define TJ 64                 // j-tile
#define NTILE (JSL / TJ)      // 32 tiles

typedef unsigned short u16;
typedef unsigned int u32;
typedef __attribute__((ext_vector_type(8))) short short8;
typedef __attribute__((ext_vector_type(4))) float floatx4;

__device__ __forceinline__ u16 bf16_rne(float f) {
  uint32_t u = __float_as_uint(f);
  u += 0x7fff + ((u >> 16) & 1);
  return (u16)(u >> 16);
}

__device__ __forceinline__ void gl_lds16(const void* g, void* l) {
  __builtin_amdgcn_global_load_lds(
      (const __attribute__((address_space(1))) void*)g,
      (__attribute__((address_space(3))) void*)l, 16, 0, 0);
}

// ---------------------------------------------------------------------------
// Kernel 1: h = x@W (fp32); hT3 bf16 tiled [jb][nt][m*4+q][8]; src/dst.
// (unchanged)
// ---------------------------------------------------------------------------
__global__ __launch_bounds__(256) void k_proj(const float* __restrict__ x,
                                              const float* __restrict__ W,
                                              const float* __restrict__ a,
                                              u16* __restrict__ hT3,
                                              float* __restrict__ srcv,
                                              float* __restrict__ dstv) {
  __shared__ float xs[8 * FIN];
  __shared__ float partS[4][4], partD[4][4];
  const int t = threadIdx.x;
  const int R0 = blockIdx.x * 8;

  const float4* xv = (const float4*)(x + (size_t)R0 * FIN);
  float4* xsv = (float4*)xs;
  xsv[t] = xv[t];
  xsv[t + 256] = xv[t + 256];
  __syncthreads();

  const int c  = t & 127;
  const int rg = (t >> 7) * 4;

  float acc[4] = {0.f, 0.f, 0.f, 0.f};
  float wa[4], wb[4];
  #pragma unroll
  for (int j = 0; j < 4; ++j) wa[j] = W[j * FOUT + c];
  #pragma unroll
  for (int j = 0; j < 4; ++j) wb[j] = W[(4 + j) * FOUT + c];

  for (int k4 = 0; k4 < FIN / 4; ++k4) {
    float wc[4];
    #pragma unroll
    for (int j = 0; j < 4; ++j) { wc[j] = wa[j]; wa[j] = wb[j]; }
    const int kn = (k4 + 2 < FIN / 4) ? k4 + 2 : k4;
    #pragma unroll
    for (int j = 0; j < 4; ++j) wb[j] = W[(kn * 4 + j) * FOUT + c];
    #pragma unroll
    for (int i = 0; i < 4; ++i) {
      const float4 xq = *(const float4*)&xs[(rg + i) * FIN + k4 * 4];
      acc[i] += xq.x * wc[0] + xq.y * wc[1] + xq.z * wc[2] + xq.w * wc[3];
    }
  }

  {
    const int j = R0 + rg;
    const int jb = j >> 5, q = (j >> 3) & 3, jj = j & 7;
    const int m = c & 15, nt = c >> 4;
    union { u16 u[4]; uint2 v; } pk;
    #pragma unroll
    for (int i = 0; i < 4; ++i) pk.u[i] = bf16_rne(acc[i]);
    *(uint2*)(hT3 + (size_t)(((jb * 8 + nt) * 64) + (m * 4 + q)) * 8 + jj) = pk.v;
  }

  const float a1 = a[c], a2 = a[FOUT + c];
  float s4[4], d4[4];
  #pragma unroll
  for (int i = 0; i < 4; ++i) { s4[i] = acc[i] * a1; d4[i] = acc[i] * a2; }
  #pragma unroll
  for (int off = 32; off > 0; off >>= 1) {
    #pragma unroll
    for (int i = 0; i < 4; ++i) {
      s4[i] += __shfl_down(s4[i], off);
      d4[i] += __shfl_down(d4[i], off);
    }
  }
  const int wv = t >> 6, lane = t & 63;
  if (lane == 0) {
    #pragma unroll
    for (int i = 0; i < 4; ++i) { partS[wv][i] = s4[i]; partD[wv][i] = d4[i]; }
  }
  __syncthreads();
  if (t < 16) {
    const int i = t & 3, rg2 = (t >> 2) & 1, which = t >> 3;
    if (which == 0) srcv[R0 + rg2 * 4 + i] = partS[rg2*2][i] + partS[rg2*2+1][i];
    else            dstv[R0 + rg2 * 4 + i] = partD[rg2*2][i] + partD[rg2*2+1][i];
  }
}

// ---------------------------------------------------------------------------
// Kernel 2 (k_mask): adj (268 MB int32) -> bitmask (8 MB). The ONLY consumer
// of the compulsory adj stream, in the best possible shape: per 64 j's one
// coalesced dword load/lane (wave = 256 B contiguous) + one v_cmp + __ballot
// (64 bits = exactly 2 consecutive mask words). 32 independent loads in
// flight per wave. mask layout: [row][jb] (1 KB/row), wave stores 256 B
// contiguous per 2048-j chunk. Grid 2048 x 256: wave = one full row.
// ---------------------------------------------------------------------------
__global__ __launch_bounds__(256, 4) void k_mask(const int* __restrict__ adj,
                                                 u32* __restrict__ mask) {
  const int t = threadIdx.x, wv = t >> 6, lane = t & 63;
  const int row = blockIdx.x * 4 + wv;
  const int* ar = adj + (size_t)row * N;
  u32* mr = mask + (size_t)row * (N / 32);
  const int lh = lane >> 1, ll = lane & 1;

  #pragma unroll 1
  for (int c = 0; c < 4; ++c) {
    int v[32];
    #pragma unroll
    for (int k = 0; k < 32; ++k) v[k] = ar[c * 2048 + k * 64 + lane];
    u32 w = 0;
    #pragma unroll
    for (int k = 0; k < 32; ++k) {
      const unsigned long long b = __ballot(v[k] > 0);
      const u32 cand = ll ? (u32)(b >> 32) : (u32)b;
      w = (lh == k) ? cand : w;          // lane 2k keeps lo, 2k+1 keeps hi
    }
    mr[c * 64 + lane] = w;               // words jb = c*64 + lane
  }
}

// ---------------------------------------------------------------------------
// Kernel 3 (k_gat): round-8 hybrid (1 barrier/tile, hT3 DMA-staged into
// double-buffered LDS, A-frags computed per-lane in registers) with adj
// replaced by the bitmask: per tile each lane loads ONE uint2 (its row's 2
// mask words, L1/L2-resident 32 KB/block) + 4 float4 dst (L2). Nothing on
// vmcnt has HBM latency; the DMA is barrier-covered with a full tile of
// cover. Waves: 2 row-groups x 2 col-halves. Grid bm(0..255) x jp(0..3).
// ---------------------------------------------------------------------------
__global__ __launch_bounds__(256, 4) void k_gat(const u32* __restrict__ mask,
                                                const u16* __restrict__ hT3,
                                                const float* __restrict__ srcv,
                                                const float* __restrict__ dstv,
                                                float* __restrict__ P,
                                                float* __restrict__ lp) {
  __shared__ u16 hS[2][8192];      // 2 x 16 KB staged hT tiles
  const int t = threadIdx.x, wv = t >> 6, lane = t & 63;
  const int q = lane >> 4, m = lane & 15;
  const int rg = wv & 1;           // row-group (16 rows)
  const int cg = wv >> 1;          // col-half (64 cols)
  const int bm = blockIdx.x & 255;
  const int jp = blockIdx.x >> 8;
  const int R0 = bm * 32;
  const int j0 = jp * JSL;
  const int Lq = m * 4 + q;
  const int row = R0 + rg * 16 + m;

  const float srcm = srcv[row];
  const u32*   mrow = mask + (size_t)row * (N / 32) + (j0 >> 5);
  const float* dstp = dstv + j0 + q * 8;
  const size_t jb00 = (size_t)(j0 >> 5);

  floatx4 acc[4];
  #pragma unroll
  for (int nt = 0; nt < 4; ++nt) acc[nt] = (floatx4){0.f, 0.f, 0.f, 0.f};
  float lsum = 0.f;

  #define STAGE(I, BUF)                                                        \
  {                                                                            \
    _Pragma("unroll")                                                          \
    for (int cc = 0; cc < 4; ++cc) {                                           \
      const int kc = wv * 4 + cc;                                              \
      const int jbl = kc >> 3, nt_ = kc & 7;                                   \
      const u16* srcp = hT3 + ((jb00 + (size_t)(I) * 2 + jbl) * 8 + nt_) * 512 \
                        + (size_t)lane * 8;                                    \
      gl_lds16(srcp, &hS[BUF][kc * 512]);                                      \
    }                                                                          \
  }

  #define TILE_WORK(I, BUF)                                                    \
  {                                                                            \
    const uint2  mw = *(const uint2*)(mrow + (I) * 2);                         \
    const float4 D0 = *(const float4*)(dstp + (I) * 64);                       \
    const float4 D1 = *(const float4*)(dstp + (I) * 64 + 4);                   \
    const float4 D2 = *(const float4*)(dstp + (I) * 64 + 32);                  \
    const float4 D3 = *(const float4*)(dstp + (I) * 64 + 36);                  \
    _Pragma("unroll")                                                          \
    for (int ks = 0; ks < 2; ++ks) {                                           \
      const u32 byte8 = ((ks ? mw.y : mw.x) >> (q * 8)) & 0xffu;               \
      const float4 Da = ks ? D2 : D0, Db = ks ? D3 : D1;                       \
      const float df[8] = {Da.x, Da.y, Da.z, Da.w, Db.x, Db.y, Db.z, Db.w};    \
      union { u16 u[8]; short8 s; } pk;                                        \
      _Pragma("unroll")                                                        \
      for (int e = 0; e < 8; ++e) {                                            \
        float v = srcm + df[e];                                                \
        v = fmaxf(v, ALPHA * v);                                               \
        const float p = ((byte8 >> e) & 1u) ? __expf(v) : 0.f;                 \
        lsum += p;                                                             \
        pk.u[e] = bf16_rne(p);                                                 \
      }                                                                        \
      _Pragma("unroll")                                                        \
      for (int nt = 0; nt < 4; ++nt) {                                         \
        const short8 bf =                                                      \
            *(const short8*)&hS[BUF][(ks * 8 + cg * 4 + nt) * 512 + Lq * 8];   \
        acc[nt] =                                                              \
            __builtin_amdgcn_mfma_f32_16x16x32_bf16(pk.s, bf, acc[nt], 0, 0, 0); \
      }                                                                        \
    }                                                                          \
  }

  STAGE(0, 0)
  for (int i = 0; i < NTILE; i += 2) {
    __syncthreads();                       // drains DMA(i): full tile of cover
    if (i + 1 < NTILE) STAGE(i + 1, 1)
    TILE_WORK(i, 0)
    __syncthreads();                       // drains DMA(i+1)
    if (i + 2 < NTILE) STAGE(i + 2, 0)
    TILE_WORK(i + 1, 1)
  }
  #undef STAGE
  #undef TILE_WORK

  // row-sum over the 4 q-lanes sharing row m (col-half 0 publishes)
  lsum += __shfl_xor(lsum, 16);
  lsum += __shfl_xor(lsum, 32);
  if (cg == 0 && lane < 16)
    lp[(size_t)jp * N + R0 + rg * 16 + lane] = lsum;

  // partial store: rows R0+rg*16+(q*4+ri), cols cg*64 + nt*16 + m
  float* Pp = P + ((size_t)jp * N + R0 + rg * 16) * FOUT + cg * 64;
  #pragma unroll
  for (int nt = 0; nt < 4; ++nt)
    #pragma unroll
    for (int ri = 0; ri < 4; ++ri)
      Pp[(size_t)(q * 4 + ri) * FOUT + nt * 16 + m] = acc[nt][ri];
}

// ---------------------------------------------------------------------------
// Kernel 4: combine JP partials, normalize by row-sum.
// ---------------------------------------------------------------------------
__global__ __launch_bounds__(256) void k_norm(const float* __restrict__ P,
                                              const float* __restrict__ lp,
                                              float* __restrict__ out) {
  const int idx = blockIdx.x * 256 + threadIdx.x;
  const int rr = idx >> 5;
  const int c4 = (idx & 31) * 4;
  float l = 0.f;
  #pragma unroll
  for (int j = 0; j < JP; ++j) l += lp[(size_t)j * N + rr];
  const float inv = 1.0f / l;
  float4 s = {0.f, 0.f, 0.f, 0.f};
  #pragma unroll
  for (int j = 0; j < JP; ++j) {
    const float4 p = *(const float4*)(P + ((size_t)j * N + rr) * FOUT + c4);
    s.x += p.x; s.y += p.y; s.z += p.z; s.w += p.w;
  }
  s.x *= inv; s.y *= inv; s.z *= inv; s.w *= inv;
  *(float4*)(out + (size_t)rr * FOUT + c4) = s;
}

extern "C" void kernel_launch(void* const* d_in, const int* in_sizes, int n_in,
                              void* d_out, int out_size, void* d_ws, size_t ws_size,
                              hipStream_t stream) {
  const float* x   = (const float*)d_in[0];
  const int*   adj = (const int*)d_in[1];
  const float* W   = (const float*)d_in[2];
  const float* a   = (const float*)d_in[3];
  float* out = (float*)d_out;

  char* ws = (char*)d_ws;
  u16*   hT3  = (u16*)ws;     ws += (size_t)FOUT * N * sizeof(u16);            // 2 MB
  float* srcv = (float*)ws;   ws += (size_t)N * sizeof(float);
  float* dstv = (float*)ws;   ws += (size_t)N * sizeof(float);
  u32*   mask = (u32*)ws;     ws += (size_t)N * (N / 32) * sizeof(u32);        // 8 MB
  float* P    = (float*)ws;   ws += (size_t)JP * N * FOUT * sizeof(float);     // 16 MB
  float* lp   = (float*)ws;   ws += (size_t)JP * N * sizeof(float);

  k_proj<<<N / 8, 256, 0, stream>>>(x, W, a, hT3, srcv, dstv);
  k_mask<<<N / 4, 256, 0, stream>>>(adj, mask);
  k_gat <<<256 * JP, 256, 0, stream>>>(mask, hT3, srcv, dstv, P, lp);
  k_norm<<<(N * FOUT / 4) / 256, 256, 0, stream>>>(P, lp, out);
}